// Round 4
// baseline (212.209 us; speedup 1.0000x reference)
//
#include <hip/hip_runtime.h>

// B=4, T=2048, C=1024, H=16, D=64.  M = B*T = 8192.
// cast f32->bf16; QKV GEMM (bf16 MFMA, XCD-swizzled); V transpose; 8-wave 32x32
// swapped-operand causal flash attention (in-register softmax, defer-max); out GEMM + bias.

typedef __attribute__((ext_vector_type(8))) __bf16 bf16x8;
typedef __attribute__((ext_vector_type(4))) float f32x4;
typedef __attribute__((ext_vector_type(16))) float f32x16;

__device__ __forceinline__ unsigned short f2bf(float f) {
  union { float f; unsigned u; } v; v.f = f;
  unsigned r = v.u + 0x7fffu + ((v.u >> 16) & 1u);   // RNE
  return (unsigned short)(r >> 16);
}

__device__ __forceinline__ unsigned cvtpk(float lo, float hi) {
  unsigned r;
  asm("v_cvt_pk_bf16_f32 %0, %1, %2" : "=v"(r) : "v"(lo), "v"(hi));
  return r;
}

__device__ __forceinline__ void gld16(const void* g, void* l) {
  __builtin_amdgcn_global_load_lds(
      (const __attribute__((address_space(1))) void*)g,
      (__attribute__((address_space(3))) void*)l, 16, 0, 0);
}

__device__ __forceinline__ f32x4 mfma16(bf16x8 a, bf16x8 b, f32x4 c) {
  return __builtin_amdgcn_mfma_f32_16x16x32_bf16(a, b, c, 0, 0, 0);
}
__device__ __forceinline__ f32x16 mfma32(bf16x8 a, bf16x8 b, f32x16 c) {
  return __builtin_amdgcn_mfma_f32_32x32x16_bf16(a, b, c, 0, 0, 0);
}

__global__ __launch_bounds__(256) void cast_f32_bf16(
    const float* __restrict__ src, unsigned short* __restrict__ dst, int n) {
  int i = (blockIdx.x * 256 + threadIdx.x) * 4;
  if (i >= n) return;
  float4 v = *(const float4*)(src + i);
  ushort4 o;
  o.x = f2bf(v.x); o.y = f2bf(v.y); o.z = f2bf(v.z); o.w = f2bf(v.w);
  *(ushort4*)(dst + i) = o;
}

// C[m][n] = sum_k A[m][k]*Bm[n][k].  128x128 tile, BK=64, 4 waves.
// Bijective XCD swizzle: each XCD gets 8 contiguous M-panels (A L2-resident).
// MODE 0: scatter to q/k/v [B,H,T,D], q scaled by 0.125*log2(e).
// MODE 1: out = acc + bias[n], f32.
template <int MODE>
__global__ __launch_bounds__(256) void gemm_bt(
    const unsigned short* __restrict__ A, const unsigned short* __restrict__ Bm,
    unsigned short* __restrict__ qo, unsigned short* __restrict__ ko,
    unsigned short* __restrict__ vo,
    const float* __restrict__ bias, float* __restrict__ fout) {
  __shared__ unsigned short Al[128 * 64];
  __shared__ unsigned short Bl[128 * 64];
  const int tid = threadIdx.x;
  const int w = tid >> 6, l = tid & 63, lr = l & 15, lg = l >> 4;
  constexpr int GX = (MODE == 0) ? 24 : 8;
  constexpr int NWG = GX * 64;
  const int L = blockIdx.x + blockIdx.y * GX;
  const int logical = (L & 7) * (NWG >> 3) + (L >> 3);   // bijective (NWG%8==0)
  const int m0 = (logical / GX) * 128, n0 = (logical % GX) * 128;
  const int wm = w >> 1, wn = w & 1;
  f32x4 acc[4][4];
  f32x4 zero = {0.f, 0.f, 0.f, 0.f};
#pragma unroll
  for (int i = 0; i < 4; i++)
#pragma unroll
    for (int j = 0; j < 4; j++) acc[i][j] = zero;

  for (int kk = 0; kk < 1024; kk += 64) {
#pragma unroll
    for (int c = 0; c < 4; c++) {
      int e = c * 2048 + tid * 8;
      int r = e >> 6, col = e & 63;
      gld16(A + (size_t)(m0 + r) * 1024 + kk + col, (char*)Al + (size_t)e * 2);
      gld16(Bm + (size_t)(n0 + r) * 1024 + kk + col, (char*)Bl + (size_t)e * 2);
    }
    __syncthreads();
#pragma unroll
    for (int c = 0; c < 2; c++) {
      bf16x8 af[4], bfr[4];
#pragma unroll
      for (int mt = 0; mt < 4; mt++)
        af[mt] = *(const bf16x8*)(Al + (wm * 64 + mt * 16 + lr) * 64 + c * 32 + lg * 8);
#pragma unroll
      for (int nt = 0; nt < 4; nt++)
        bfr[nt] = *(const bf16x8*)(Bl + (wn * 64 + nt * 16 + lr) * 64 + c * 32 + lg * 8);
#pragma unroll
      for (int mt = 0; mt < 4; mt++)
#pragma unroll
        for (int nt = 0; nt < 4; nt++)
          acc[mt][nt] = mfma16(af[mt], bfr[nt], acc[mt][nt]);
    }
    __syncthreads();
  }

#pragma unroll
  for (int mt = 0; mt < 4; mt++) {
#pragma unroll
    for (int nt = 0; nt < 4; nt++) {
      int n = n0 + wn * 64 + nt * 16 + lr;
      int mbase = m0 + wm * 64 + mt * 16 + lg * 4;
      if (MODE == 0) {
        int ty = n >> 10, cc = n & 1023;
        int h = cc >> 6, dd = cc & 63;
        unsigned short* dst = (ty == 0) ? qo : ((ty == 1) ? ko : vo);
        float sc = (ty == 0) ? 0.18033688011111687f : 1.0f;  // (1/8)*log2(e)
#pragma unroll
        for (int i = 0; i < 4; i++) {
          int m = mbase + i;
          int b = m >> 11, tt = m & 2047;
          dst[(((size_t)(b * 16 + h)) * 2048 + tt) * 64 + dd] =
              f2bf(acc[mt][nt][i] * sc);
        }
      } else {
        float bv = bias[n];
#pragma unroll
        for (int i = 0; i < 4; i++) {
          int m = mbase + i;
          fout[(size_t)m * 1024 + n] = acc[mt][nt][i] + bv;
        }
      }
    }
  }
}

// v [B,H,T,D] -> vt [B,H,D,T]
__global__ __launch_bounds__(256) void transpose_v64(
    const unsigned short* __restrict__ v, unsigned short* __restrict__ vt) {
  __shared__ unsigned short tile[64 * 72];
  int bh = blockIdx.y, t0 = blockIdx.x * 64;
  const unsigned short* vp = v + (size_t)bh * 2048 * 64;
  unsigned short* vtp = vt + (size_t)bh * 64 * 2048;
  int tid = threadIdx.x;
#pragma unroll
  for (int it = 0; it < 2; ++it) {
    int s = tid + it * 256;
    int r = s >> 3, c = (s & 7) * 8;
    *(uint4*)(tile + r * 72 + c) = *(const uint4*)(vp + (size_t)(t0 + r) * 64 + c);
  }
  __syncthreads();
#pragma unroll
  for (int it = 0; it < 2; ++it) {
    int s = tid + it * 256;
    int d = s >> 3, c = (s & 7) * 8;
    unsigned short tmp[8];
#pragma unroll
    for (int j = 0; j < 8; j++) tmp[j] = tile[(c + j) * 72 + d];
    *(uint4*)(vtp + (size_t)d * 2048 + t0 + c) = *(uint4*)tmp;
  }
}

// swizzled LDS read of an MFMA fragment: row stride 128B, byte ^= (row&7)<<4
__device__ __forceinline__ bf16x8 ldsw(const char* base, int row, int cb) {
  return *(const bf16x8*)(base + row * 128 + (cb ^ ((row & 7) << 4)));
}

// Causal flash attention, 8 waves x 32 q-rows (strided: q = q0 + 8*lane + w).
// KV tiles of 64, swapped-operand 32x32x16 MFMA, in-register exp2 softmax,
// defer-max (scalar).  q pre-scaled by 0.125*log2e.
__global__ __launch_bounds__(512, 4) void attn_causal(
    const unsigned short* __restrict__ qg, const unsigned short* __restrict__ kg,
    const unsigned short* __restrict__ vtg, unsigned short* __restrict__ og) {
  __shared__ char lds[32768];   // dbuf: [K 8K | Vt 8K] x2; reused for out bounce
  const int tid = threadIdx.x;
  const int w = tid >> 6, l = tid & 63, lo = l & 31, hi = l >> 5;
  const int bh = blockIdx.x;
  const int qc = 7 - blockIdx.y;           // LPT: heavy q-chunks dispatch first
  const int q0 = qc * 256;
  const int nkv = qc * 4 + 4;
  const int b = bh >> 4, h = bh & 15;
  const char* kpB = (const char*)(kg + (size_t)bh * 131072);
  const char* vpB = (const char*)(vtg + (size_t)bh * 131072);
  const unsigned short* qp = qg + (size_t)bh * 131072;
  const int qrow = q0 + 8 * lo + w;

  bf16x8 qf[4];
#pragma unroll
  for (int c = 0; c < 4; ++c)
    qf[c] = *(const bf16x8*)(qp + (size_t)qrow * 64 + hi * 8 + c * 16);

  f32x16 ov[2];
#pragma unroll
  for (int r = 0; r < 16; ++r) { ov[0][r] = 0.f; ov[1][r] = 0.f; }
  const f32x16 zz = {0.f, 0.f, 0.f, 0.f, 0.f, 0.f, 0.f, 0.f,
                     0.f, 0.f, 0.f, 0.f, 0.f, 0.f, 0.f, 0.f};
  float m = -__builtin_inff(), lsum = 0.f;

  const int srow = tid >> 3;
  const int scb = ((tid & 7) * 16) ^ ((srow & 7) << 4);

  gld16(kpB + (size_t)srow * 128 + scb, lds + tid * 16);
  gld16(vpB + (size_t)srow * 4096 + scb, lds + 8192 + tid * 16);
  __syncthreads();

  for (int kt = 0; kt < nkv; ++kt) {
    const int k0 = kt * 64;
    if (kt + 1 < nkv) {
      char* nb = lds + ((kt + 1) & 1) * 16384;
      gld16(kpB + (size_t)(k0 + 64 + srow) * 128 + scb, nb + tid * 16);
      gld16(vpB + (size_t)srow * 4096 + (size_t)(k0 + 64) * 2 + scb, nb + 8192 + tid * 16);
    }
    const char* Kbuf = lds + (kt & 1) * 16384;
    const char* Vbuf = Kbuf + 8192;

    // S^T = K·Q^T (two 32-row k blocks, 4 d-chunks); first chunk uses zero acc
    f32x16 sv[2];
#pragma unroll
    for (int c = 0; c < 4; ++c) {
      bf16x8 kf0 = ldsw(Kbuf, lo, hi * 16 + c * 32);
      bf16x8 kf1 = ldsw(Kbuf, 32 + lo, hi * 16 + c * 32);
      if (c == 0) {
        sv[0] = mfma32(kf0, qf[0], zz);
        sv[1] = mfma32(kf1, qf[0], zz);
      } else {
        sv[0] = mfma32(kf0, qf[c], sv[0]);
        sv[1] = mfma32(kf1, qf[c], sv[1]);
      }
    }

    if (kt >= nkv - 4) {   // causal mask (last 4 tiles only)
#pragma unroll
      for (int t = 0; t < 2; ++t)
#pragma unroll
        for (int r = 0; r < 16; ++r) {
          int kgl = k0 + t * 32 + (r & 3) + 8 * (r >> 2) + 4 * hi;
          if (kgl > qrow) sv[t][r] = -__builtin_inff();
        }
    }

    // tile max via pairwise tree (31 fmax, depth 6)
    float mx[16];
#pragma unroll
    for (int i = 0; i < 16; ++i) mx[i] = fmaxf(sv[0][i], sv[1][i]);
#pragma unroll
    for (int s = 8; s > 0; s >>= 1)
#pragma unroll
      for (int i = 0; i < s; ++i) mx[i] = fmaxf(mx[i], mx[i + s]);
    float tm = fmaxf(mx[0], __shfl_xor(mx[0], 32, 64));

    // defer-max: rescale only when the running max grew by >8 (exp2 domain).
    // First tile: m = -inf -> branch always taken.
    if (!__all(tm <= m + 8.f)) {
      float nm = fmaxf(fmaxf(m, tm), -1e30f);   // clamp: fully-masked lanes stay sane
      float f = exp2f(m - nm);
      m = nm;
      lsum *= f;
#pragma unroll
      for (int r = 0; r < 16; ++r) { ov[0][r] *= f; ov[1][r] *= f; }
    }

    float ps = 0.f;
#pragma unroll
    for (int t = 0; t < 2; ++t)
#pragma unroll
      for (int r = 0; r < 16; ++r) {
        float p = exp2f(sv[t][r] - m);
        sv[t][r] = p;
        ps += p;
      }
    lsum += ps;

    // P -> bf16 B-frags (cvt_pk + permlane32_swap), then O^T += Vt·P^T
#pragma unroll
    for (int c = 0; c < 4; ++c) {
      const int t = c >> 1, rb = (c & 1) * 8;
      unsigned wA = cvtpk(sv[t][rb + 0], sv[t][rb + 1]);
      unsigned wB = cvtpk(sv[t][rb + 2], sv[t][rb + 3]);
      unsigned wC = cvtpk(sv[t][rb + 4], sv[t][rb + 5]);
      unsigned wD = cvtpk(sv[t][rb + 6], sv[t][rb + 7]);
      asm volatile("v_permlane32_swap_b32 %0, %1" : "+v"(wA), "+v"(wC));
      asm volatile("v_permlane32_swap_b32 %0, %1" : "+v"(wB), "+v"(wD));
      union { uint4 u; bf16x8 h; } pc;
      pc.u.x = wA; pc.u.y = wB; pc.u.z = wC; pc.u.w = wD;
      bf16x8 vf0 = ldsw(Vbuf, lo, hi * 16 + c * 32);
      bf16x8 vf1 = ldsw(Vbuf, 32 + lo, hi * 16 + c * 32);
      ov[0] = mfma32(vf0, pc.h, ov[0]);
      ov[1] = mfma32(vf1, pc.h, ov[1]);
    }
    __syncthreads();
  }

  // epilogue: normalize, bounce through LDS (swizzled) for coalesced stores
  float lt = lsum + __shfl_xor(lsum, 32, 64);
  float inv = 1.0f / lt;
  char* outl = lds + w * 4096;   // per-wave 4KB region: [32 q][64 d] bf16
#pragma unroll
  for (int t2 = 0; t2 < 2; ++t2)
#pragma unroll
    for (int rp = 0; rp < 8; ++rp) {
      const int r = rp * 2;
      const int d0 = (r & 3) + 8 * (r >> 2) + 4 * hi + 32 * t2;
      unsigned pw = cvtpk(ov[t2][r] * inv, ov[t2][r + 1] * inv);
      *(unsigned*)(outl + lo * 128 + ((d0 * 2) ^ ((lo & 7) << 4))) = pw;
    }
  __syncthreads();
  {
    const int qi = l >> 1, cbb = (l & 1) * 64;
    const int t = q0 + 8 * qi + w;
    unsigned short* gp = og + ((size_t)(b * 2048 + t)) * 1024 + h * 64 + (cbb >> 1);
#pragma unroll
    for (int i = 0; i < 4; ++i) {
      uint4 vdat = *(const uint4*)(outl + qi * 128 + ((cbb + i * 16) ^ ((qi & 7) << 4)));
      *(uint4*)(gp + i * 8) = vdat;
    }
  }
}

extern "C" void kernel_launch(void* const* d_in, const int* in_sizes, int n_in,
                              void* d_out, int out_size, void* d_ws, size_t ws_size,
                              hipStream_t stream) {
  const float* x = (const float*)d_in[0];
  const float* Wqkv = (const float*)d_in[1];
  const float* Wout = (const float*)d_in[2];
  const float* bout = (const float*)d_in[3];
  float* out = (float*)d_out;
  char* ws = (char*)d_ws;

  unsigned short* xb = (unsigned short*)(ws);
  unsigned short* wqb = (unsigned short*)(ws + 16777216);
  unsigned short* wob = (unsigned short*)(ws + 23068672);
  unsigned short* qb = (unsigned short*)(ws + 25165824);
  unsigned short* kb = (unsigned short*)(ws + 41943040);
  unsigned short* vb = (unsigned short*)(ws + 58720256);
  unsigned short* vtb = xb;   // x dead after QKV GEMM
  unsigned short* ogb = vb;   // v dead after transpose

  cast_f32_bf16<<<8192, 256, 0, stream>>>(x, xb, 8388608);
  cast_f32_bf16<<<3072, 256, 0, stream>>>(Wqkv, wqb, 3145728);
  cast_f32_bf16<<<1024, 256, 0, stream>>>(Wout, wob, 1048576);

  gemm_bt<0><<<dim3(24, 64), 256, 0, stream>>>(xb, wqb, qb, kb, vb, nullptr, nullptr);
  transpose_v64<<<dim3(32, 64), 256, 0, stream>>>(vb, vtb);
  attn_causal<<<dim3(64, 8), 512, 0, stream>>>(qb, kb, vtb, ogb);
  gemm_bt<1><<<dim3(8, 64), 256, 0, stream>>>(ogb, wob, nullptr, nullptr, nullptr, bout, out);
}

// Round 5
// 200.622 us; speedup vs baseline: 1.0578x; 1.0578x over previous
//
#include <hip/hip_runtime.h>

// B=4, T=2048, C=1024, H=16, D=64.  M = B*T = 8192.
// cast f32->bf16; QKV GEMM (bf16 MFMA, XCD-swizzled); V transpose; 8-wave 32x32
// swapped-operand causal flash attention (in-register softmax, defer-max,
// complementary-pair block order); out GEMM + bias.

typedef __attribute__((ext_vector_type(8))) __bf16 bf16x8;
typedef __attribute__((ext_vector_type(4))) float f32x4;
typedef __attribute__((ext_vector_type(16))) float f32x16;

__device__ __forceinline__ unsigned short f2bf(float f) {
  union { float f; unsigned u; } v; v.f = f;
  unsigned r = v.u + 0x7fffu + ((v.u >> 16) & 1u);   // RNE
  return (unsigned short)(r >> 16);
}

__device__ __forceinline__ unsigned cvtpk(float lo, float hi) {
  unsigned r;
  asm("v_cvt_pk_bf16_f32 %0, %1, %2" : "=v"(r) : "v"(lo), "v"(hi));
  return r;
}

__device__ __forceinline__ void gld16(const void* g, void* l) {
  __builtin_amdgcn_global_load_lds(
      (const __attribute__((address_space(1))) void*)g,
      (__attribute__((address_space(3))) void*)l, 16, 0, 0);
}

__device__ __forceinline__ f32x4 mfma16(bf16x8 a, bf16x8 b, f32x4 c) {
  return __builtin_amdgcn_mfma_f32_16x16x32_bf16(a, b, c, 0, 0, 0);
}
__device__ __forceinline__ f32x16 mfma32(bf16x8 a, bf16x8 b, f32x16 c) {
  return __builtin_amdgcn_mfma_f32_32x32x16_bf16(a, b, c, 0, 0, 0);
}

__global__ __launch_bounds__(256) void cast_f32_bf16(
    const float* __restrict__ src, unsigned short* __restrict__ dst, int n) {
  int i = (blockIdx.x * 256 + threadIdx.x) * 4;
  if (i >= n) return;
  float4 v = *(const float4*)(src + i);
  ushort4 o;
  o.x = f2bf(v.x); o.y = f2bf(v.y); o.z = f2bf(v.z); o.w = f2bf(v.w);
  *(ushort4*)(dst + i) = o;
}

// C[m][n] = sum_k A[m][k]*Bm[n][k].  128x128 tile, BK=64, 4 waves.
// Bijective XCD swizzle: each XCD gets 8 contiguous M-panels (A L2-resident).
// MODE 0: scatter to q/k/v [B,H,T,D], q scaled by 0.125*log2(e).
// MODE 1: out = acc + bias[n], f32.
template <int MODE>
__global__ __launch_bounds__(256) void gemm_bt(
    const unsigned short* __restrict__ A, const unsigned short* __restrict__ Bm,
    unsigned short* __restrict__ qo, unsigned short* __restrict__ ko,
    unsigned short* __restrict__ vo,
    const float* __restrict__ bias, float* __restrict__ fout) {
  __shared__ unsigned short Al[128 * 64];
  __shared__ unsigned short Bl[128 * 64];
  const int tid = threadIdx.x;
  const int w = tid >> 6, l = tid & 63, lr = l & 15, lg = l >> 4;
  constexpr int GX = (MODE == 0) ? 24 : 8;
  constexpr int NWG = GX * 64;
  const int L = blockIdx.x + blockIdx.y * GX;
  const int logical = (L & 7) * (NWG >> 3) + (L >> 3);   // bijective (NWG%8==0)
  const int m0 = (logical / GX) * 128, n0 = (logical % GX) * 128;
  const int wm = w >> 1, wn = w & 1;
  f32x4 acc[4][4];
  f32x4 zero = {0.f, 0.f, 0.f, 0.f};
#pragma unroll
  for (int i = 0; i < 4; i++)
#pragma unroll
    for (int j = 0; j < 4; j++) acc[i][j] = zero;

  for (int kk = 0; kk < 1024; kk += 64) {
#pragma unroll
    for (int c = 0; c < 4; c++) {
      int e = c * 2048 + tid * 8;
      int r = e >> 6, col = e & 63;
      gld16(A + (size_t)(m0 + r) * 1024 + kk + col, (char*)Al + (size_t)e * 2);
      gld16(Bm + (size_t)(n0 + r) * 1024 + kk + col, (char*)Bl + (size_t)e * 2);
    }
    __syncthreads();
#pragma unroll
    for (int c = 0; c < 2; c++) {
      bf16x8 af[4], bfr[4];
#pragma unroll
      for (int mt = 0; mt < 4; mt++)
        af[mt] = *(const bf16x8*)(Al + (wm * 64 + mt * 16 + lr) * 64 + c * 32 + lg * 8);
#pragma unroll
      for (int nt = 0; nt < 4; nt++)
        bfr[nt] = *(const bf16x8*)(Bl + (wn * 64 + nt * 16 + lr) * 64 + c * 32 + lg * 8);
#pragma unroll
      for (int mt = 0; mt < 4; mt++)
#pragma unroll
        for (int nt = 0; nt < 4; nt++)
          acc[mt][nt] = mfma16(af[mt], bfr[nt], acc[mt][nt]);
    }
    __syncthreads();
  }

#pragma unroll
  for (int mt = 0; mt < 4; mt++) {
#pragma unroll
    for (int nt = 0; nt < 4; nt++) {
      int n = n0 + wn * 64 + nt * 16 + lr;
      int mbase = m0 + wm * 64 + mt * 16 + lg * 4;
      if (MODE == 0) {
        int ty = n >> 10, cc = n & 1023;
        int h = cc >> 6, dd = cc & 63;
        unsigned short* dst = (ty == 0) ? qo : ((ty == 1) ? ko : vo);
        float sc = (ty == 0) ? 0.18033688011111687f : 1.0f;  // (1/8)*log2(e)
#pragma unroll
        for (int i = 0; i < 4; i++) {
          int m = mbase + i;
          int b = m >> 11, tt = m & 2047;
          dst[(((size_t)(b * 16 + h)) * 2048 + tt) * 64 + dd] =
              f2bf(acc[mt][nt][i] * sc);
        }
      } else {
        float bv = bias[n];
#pragma unroll
        for (int i = 0; i < 4; i++) {
          int m = mbase + i;
          fout[(size_t)m * 1024 + n] = acc[mt][nt][i] + bv;
        }
      }
    }
  }
}

// v [B,H,T,D] -> vt [B,H,D,T]
__global__ __launch_bounds__(256) void transpose_v64(
    const unsigned short* __restrict__ v, unsigned short* __restrict__ vt) {
  __shared__ unsigned short tile[64 * 72];
  int bh = blockIdx.y, t0 = blockIdx.x * 64;
  const unsigned short* vp = v + (size_t)bh * 2048 * 64;
  unsigned short* vtp = vt + (size_t)bh * 64 * 2048;
  int tid = threadIdx.x;
#pragma unroll
  for (int it = 0; it < 2; ++it) {
    int s = tid + it * 256;
    int r = s >> 3, c = (s & 7) * 8;
    *(uint4*)(tile + r * 72 + c) = *(const uint4*)(vp + (size_t)(t0 + r) * 64 + c);
  }
  __syncthreads();
#pragma unroll
  for (int it = 0; it < 2; ++it) {
    int s = tid + it * 256;
    int d = s >> 3, c = (s & 7) * 8;
    unsigned short tmp[8];
#pragma unroll
    for (int j = 0; j < 8; j++) tmp[j] = tile[(c + j) * 72 + d];
    *(uint4*)(vtp + (size_t)d * 2048 + t0 + c) = *(uint4*)tmp;
  }
}

// swizzled LDS read of an MFMA fragment: row stride 128B, byte ^= (row&7)<<4
__device__ __forceinline__ bf16x8 ldsw(const char* base, int row, int cb) {
  return *(const bf16x8*)(base + row * 128 + (cb ^ ((row & 7) << 4)));
}

// Causal flash attention, 8 waves x 32 q-rows (strided: q = q0 + 8*lane + w).
// KV tiles of 64, swapped-operand 32x32x16 MFMA, in-register exp2 softmax,
// defer-max.  Block order: qc = PERM[y], PERM={7,5,6,4,0,2,1,3} so co-resident
// CU pairs (slot c, slot c+256) get complementary causal loads (36 tiles each).
__global__ __launch_bounds__(512, 4) void attn_causal(
    const unsigned short* __restrict__ qg, const unsigned short* __restrict__ kg,
    const unsigned short* __restrict__ vtg, unsigned short* __restrict__ og) {
  __shared__ char lds[32768];   // dbuf: [K 8K | Vt 8K] x2; reused for out bounce
  const int tid = threadIdx.x;
  const int w = tid >> 6, l = tid & 63, lo = l & 31, hi = l >> 5;
  const int bh = blockIdx.x;
  const int qc = (0x31204657u >> (blockIdx.y * 4)) & 7;  // complementary pairs
  const int q0 = qc * 256;
  const int nkv = qc * 4 + 4;
  const int b = bh >> 4, h = bh & 15;
  const char* kpB = (const char*)(kg + (size_t)bh * 131072);
  const char* vpB = (const char*)(vtg + (size_t)bh * 131072);
  const unsigned short* qp = qg + (size_t)bh * 131072;
  const int qrow = q0 + 8 * lo + w;

  bf16x8 qf[4];
#pragma unroll
  for (int c = 0; c < 4; ++c)
    qf[c] = *(const bf16x8*)(qp + (size_t)qrow * 64 + hi * 8 + c * 16);

  f32x16 ov[2];
#pragma unroll
  for (int r = 0; r < 16; ++r) { ov[0][r] = 0.f; ov[1][r] = 0.f; }
  const f32x16 zz = {0.f, 0.f, 0.f, 0.f, 0.f, 0.f, 0.f, 0.f,
                     0.f, 0.f, 0.f, 0.f, 0.f, 0.f, 0.f, 0.f};
  float m = -__builtin_inff(), lsum = 0.f;

  const int srow = tid >> 3;
  const int scb = ((tid & 7) * 16) ^ ((srow & 7) << 4);

  gld16(kpB + (size_t)srow * 128 + scb, lds + tid * 16);
  gld16(vpB + (size_t)srow * 4096 + scb, lds + 8192 + tid * 16);
  __syncthreads();

  for (int kt = 0; kt < nkv; ++kt) {
    const int k0 = kt * 64;
    if (kt + 1 < nkv) {
      char* nb = lds + ((kt + 1) & 1) * 16384;
      gld16(kpB + (size_t)(k0 + 64 + srow) * 128 + scb, nb + tid * 16);
      gld16(vpB + (size_t)srow * 4096 + (size_t)(k0 + 64) * 2 + scb, nb + 8192 + tid * 16);
    }
    const char* Kbuf = lds + (kt & 1) * 16384;
    const char* Vbuf = Kbuf + 8192;

    // S^T = K·Q^T (two 32-row k blocks, 4 d-chunks); first chunk uses zero acc
    f32x16 sv[2];
    __builtin_amdgcn_s_setprio(1);
#pragma unroll
    for (int c = 0; c < 4; ++c) {
      bf16x8 kf0 = ldsw(Kbuf, lo, hi * 16 + c * 32);
      bf16x8 kf1 = ldsw(Kbuf, 32 + lo, hi * 16 + c * 32);
      if (c == 0) {
        sv[0] = mfma32(kf0, qf[0], zz);
        sv[1] = mfma32(kf1, qf[0], zz);
      } else {
        sv[0] = mfma32(kf0, qf[c], sv[0]);
        sv[1] = mfma32(kf1, qf[c], sv[1]);
      }
    }
    __builtin_amdgcn_s_setprio(0);

    if (kt >= nkv - 4) {   // causal mask (last 4 tiles only)
#pragma unroll
      for (int t = 0; t < 2; ++t)
#pragma unroll
        for (int r = 0; r < 16; ++r) {
          int kgl = k0 + t * 32 + (r & 3) + 8 * (r >> 2) + 4 * hi;
          if (kgl > qrow) sv[t][r] = -__builtin_inff();
        }
    }

    // tile max via pairwise tree (31 fmax, depth 6)
    float mx[16];
#pragma unroll
    for (int i = 0; i < 16; ++i) mx[i] = fmaxf(sv[0][i], sv[1][i]);
#pragma unroll
    for (int s = 8; s > 0; s >>= 1)
#pragma unroll
      for (int i = 0; i < s; ++i) mx[i] = fmaxf(mx[i], mx[i + s]);
    float tm = fmaxf(mx[0], __shfl_xor(mx[0], 32, 64));

    // defer-max: rescale only when the running max grew by >8 (exp2 domain).
    if (!__all(tm <= m + 8.f)) {
      float nm = fmaxf(fmaxf(m, tm), -1e30f);   // clamp: fully-masked lanes stay sane
      float f = exp2f(m - nm);
      m = nm;
      lsum *= f;
#pragma unroll
      for (int r = 0; r < 16; ++r) { ov[0][r] *= f; ov[1][r] *= f; }
    }

    float ps = 0.f;
#pragma unroll
    for (int t = 0; t < 2; ++t)
#pragma unroll
      for (int r = 0; r < 16; ++r) {
        float p = exp2f(sv[t][r] - m);
        sv[t][r] = p;
        ps += p;
      }
    lsum += ps;

    // P -> bf16 B-frags (cvt_pk + permlane32_swap), then O^T += Vt·P^T
    __builtin_amdgcn_s_setprio(1);
#pragma unroll
    for (int c = 0; c < 4; ++c) {
      const int t = c >> 1, rb = (c & 1) * 8;
      unsigned wA = cvtpk(sv[t][rb + 0], sv[t][rb + 1]);
      unsigned wB = cvtpk(sv[t][rb + 2], sv[t][rb + 3]);
      unsigned wC = cvtpk(sv[t][rb + 4], sv[t][rb + 5]);
      unsigned wD = cvtpk(sv[t][rb + 6], sv[t][rb + 7]);
      asm volatile("v_permlane32_swap_b32 %0, %1" : "+v"(wA), "+v"(wC));
      asm volatile("v_permlane32_swap_b32 %0, %1" : "+v"(wB), "+v"(wD));
      union { uint4 u; bf16x8 h; } pc;
      pc.u.x = wA; pc.u.y = wB; pc.u.z = wC; pc.u.w = wD;
      bf16x8 vf0 = ldsw(Vbuf, lo, hi * 16 + c * 32);
      bf16x8 vf1 = ldsw(Vbuf, 32 + lo, hi * 16 + c * 32);
      ov[0] = mfma32(vf0, pc.h, ov[0]);
      ov[1] = mfma32(vf1, pc.h, ov[1]);
    }
    __builtin_amdgcn_s_setprio(0);
    __syncthreads();
  }

  // epilogue: normalize, bounce through LDS (swizzled) for coalesced stores
  float lt = lsum + __shfl_xor(lsum, 32, 64);
  float inv = 1.0f / lt;
  char* outl = lds + w * 4096;   // per-wave 4KB region: [32 q][64 d] bf16
#pragma unroll
  for (int t2 = 0; t2 < 2; ++t2)
#pragma unroll
    for (int rp = 0; rp < 8; ++rp) {
      const int r = rp * 2;
      const int d0 = (r & 3) + 8 * (r >> 2) + 4 * hi + 32 * t2;
      unsigned pw = cvtpk(ov[t2][r] * inv, ov[t2][r + 1] * inv);
      *(unsigned*)(outl + lo * 128 + ((d0 * 2) ^ ((lo & 7) << 4))) = pw;
    }
  __syncthreads();
  {
    const int qi = l >> 1, cbb = (l & 1) * 64;
    const int t = q0 + 8 * qi + w;
    unsigned short* gp = og + ((size_t)(b * 2048 + t)) * 1024 + h * 64 + (cbb >> 1);
#pragma unroll
    for (int i = 0; i < 4; ++i) {
      uint4 vdat = *(const uint4*)(outl + qi * 128 + ((cbb + i * 16) ^ ((qi & 7) << 4)));
      *(uint4*)(gp + i * 8) = vdat;
    }
  }
}

extern "C" void kernel_launch(void* const* d_in, const int* in_sizes, int n_in,
                              void* d_out, int out_size, void* d_ws, size_t ws_size,
                              hipStream_t stream) {
  const float* x = (const float*)d_in[0];
  const float* Wqkv = (const float*)d_in[1];
  const float* Wout = (const float*)d_in[2];
  const float* bout = (const float*)d_in[3];
  float* out = (float*)d_out;
  char* ws = (char*)d_ws;

  unsigned short* xb = (unsigned short*)(ws);
  unsigned short* wqb = (unsigned short*)(ws + 16777216);
  unsigned short* wob = (unsigned short*)(ws + 23068672);
  unsigned short* qb = (unsigned short*)(ws + 25165824);
  unsigned short* kb = (unsigned short*)(ws + 41943040);
  unsigned short* vb = (unsigned short*)(ws + 58720256);
  unsigned short* vtb = xb;   // x dead after QKV GEMM
  unsigned short* ogb = vb;   // v dead after transpose

  cast_f32_bf16<<<8192, 256, 0, stream>>>(x, xb, 8388608);
  cast_f32_bf16<<<3072, 256, 0, stream>>>(Wqkv, wqb, 3145728);
  cast_f32_bf16<<<1024, 256, 0, stream>>>(Wout, wob, 1048576);

  gemm_bt<0><<<dim3(24, 64), 256, 0, stream>>>(xb, wqb, qb, kb, vb, nullptr, nullptr);
  transpose_v64<<<dim3(32, 64), 256, 0, stream>>>(vb, vtb);
  attn_causal<<<dim3(64, 8), 512, 0, stream>>>(qb, kb, vtb, ogb);
  gemm_bt<1><<<dim3(8, 64), 256, 0, stream>>>(ogb, wob, nullptr, nullptr, nullptr, bout, out);
}

// Round 7
// 182.207 us; speedup vs baseline: 1.1647x; 1.1011x over previous
//
#include <hip/hip_runtime.h>

// B=4, T=2048, C=1024, H=16, D=64.  M = B*T = 8192.
// cast f32->bf16; 256x256 8-phase QKV GEMM (T2 swizzle + counted vmcnt + setprio);
// V transpose; 8-wave 32x32 swapped-operand causal flash attention; 8-phase out GEMM.

typedef __attribute__((ext_vector_type(8))) __bf16 bf16x8;
typedef __attribute__((ext_vector_type(4))) float f32x4;
typedef __attribute__((ext_vector_type(16))) float f32x16;

__device__ __forceinline__ unsigned short f2bf(float f) {
  union { float f; unsigned u; } v; v.f = f;
  unsigned r = v.u + 0x7fffu + ((v.u >> 16) & 1u);   // RNE
  return (unsigned short)(r >> 16);
}

__device__ __forceinline__ unsigned cvtpk(float lo, float hi) {
  unsigned r;
  asm("v_cvt_pk_bf16_f32 %0, %1, %2" : "=v"(r) : "v"(lo), "v"(hi));
  return r;
}

__device__ __forceinline__ void gld16(const void* g, void* l) {
  __builtin_amdgcn_global_load_lds(
      (const __attribute__((address_space(1))) void*)g,
      (__attribute__((address_space(3))) void*)l, 16, 0, 0);
}

__device__ __forceinline__ f32x4 mfma16(bf16x8 a, bf16x8 b, f32x4 c) {
  return __builtin_amdgcn_mfma_f32_16x16x32_bf16(a, b, c, 0, 0, 0);
}
__device__ __forceinline__ f32x16 mfma32(bf16x8 a, bf16x8 b, f32x16 c) {
  return __builtin_amdgcn_mfma_f32_32x32x16_bf16(a, b, c, 0, 0, 0);
}

__global__ __launch_bounds__(256) void cast_f32_bf16(
    const float* __restrict__ src, unsigned short* __restrict__ dst, int n) {
  int i = (blockIdx.x * 256 + threadIdx.x) * 4;
  if (i >= n) return;
  float4 v = *(const float4*)(src + i);
  ushort4 o;
  o.x = f2bf(v.x); o.y = f2bf(v.y); o.z = f2bf(v.z); o.w = f2bf(v.w);
  *(ushort4*)(dst + i) = o;
}

// swizzled LDS read: row stride 128B, byte ^= (row&7)<<4 (balanced 8-slot)
__device__ __forceinline__ bf16x8 ldsw128(const char* mat, int row, int cb) {
  return *(const bf16x8*)(mat + row * 128 + (cb ^ ((row & 7) << 4)));
}

// ---- 256x256 8-phase GEMM, BK=64, 8 waves (2M x 4N), 512 threads ----
// LDS 128KB: slot0 {A 32K | B 32K} slot1 {A 32K | B 32K}; even tiles slot0, odd slot1.
// Read halves == staged halves: A m-half h = rows [h*128, h*128+128)  (fixes R6's
// WAR race where stage(h0)@P2 overwrote rows 64-127 still read at P3).
// vmcnt(6) only at phases 4/8; never 0 in steady state.

#define PH_SYNC_A() do { __builtin_amdgcn_s_barrier();              \
    asm volatile("s_waitcnt lgkmcnt(0)" ::: "memory");              \
    __builtin_amdgcn_sched_barrier(0); } while (0)
#define PH_SYNC_B() do { __builtin_amdgcn_s_barrier();              \
    __builtin_amdgcn_sched_barrier(0); } while (0)
#define VMC6() asm volatile("s_waitcnt vmcnt(6)" ::: "memory")
#define VMC0() asm volatile("s_waitcnt vmcnt(0)" ::: "memory")

#define QUAD(MH, NH, AF, BF) do {                                   \
    __builtin_amdgcn_s_setprio(1);                                  \
    _Pragma("unroll") for (int mt = 0; mt < 4; ++mt)                \
    _Pragma("unroll") for (int nt = 0; nt < 2; ++nt)                \
    _Pragma("unroll") for (int kk = 0; kk < 2; ++kk)                \
      acc[(MH)*4+mt][(NH)*2+nt] =                                   \
          mfma16(AF[mt][kk], BF[nt][kk], acc[(MH)*4+mt][(NH)*2+nt]);\
    __builtin_amdgcn_s_setprio(0);                                  \
  } while (0)

// stage one 128-row half-tile (16KB): LDS dest linear, global source pre-swizzled
__device__ __forceinline__ void stage_half(const char* gbase, char* mat,
                                           int kt, int half, int tid) {
#pragma unroll
  for (int q = 0; q < 2; ++q) {
    const int r = half * 128 + q * 64 + (tid >> 3);
    const int cb = (tid & 7) * 16;
    gld16(gbase + (size_t)r * 2048 + kt * 128 + (cb ^ ((r & 7) << 4)),
          mat + r * 128 + cb);
  }
}

// A fragment read: m-half mh = rows [mh*128, mh*128+128); wave wm owns 64 rows inside
__device__ __forceinline__ void rdA(bf16x8 aF[4][2], const char* mat,
                                    int wm, int mh, int lr, int lg) {
#pragma unroll
  for (int mt = 0; mt < 4; ++mt) {
    const int row = mh * 128 + wm * 64 + mt * 16 + lr;
#pragma unroll
    for (int kk = 0; kk < 2; ++kk)
      aF[mt][kk] = ldsw128(mat, row, kk * 64 + lg * 16);
  }
}
__device__ __forceinline__ void rdB(bf16x8 bF[2][2], const char* mat,
                                    int wn, int nh, int lr, int lg) {
#pragma unroll
  for (int nt = 0; nt < 2; ++nt) {
    const int row = wn * 64 + nh * 32 + nt * 16 + lr;
#pragma unroll
    for (int kk = 0; kk < 2; ++kk)
      bF[nt][kk] = ldsw128(mat, row, kk * 64 + lg * 16);
  }
}

template <int MODE>
__global__ __launch_bounds__(512, 2) void gemm8p(
    const unsigned short* __restrict__ A, const unsigned short* __restrict__ Bm,
    unsigned short* __restrict__ qo, unsigned short* __restrict__ ko,
    unsigned short* __restrict__ vo,
    const float* __restrict__ bias, float* __restrict__ fout) {
  __shared__ char lds[131072];
  const int tid = threadIdx.x;
  const int w = tid >> 6, l = tid & 63, lr = l & 15, lg = l >> 4;
  const int wm = w >> 2, wn = w & 3;
  constexpr int GX = (MODE == 0) ? 12 : 4;
  constexpr int NWG = GX * 32;
  const int L = blockIdx.x + blockIdx.y * GX;
  const int logical = (L & 7) * (NWG >> 3) + (L >> 3);   // bijective (NWG%8==0)
  const int m0 = (logical / GX) * 256, n0 = (logical % GX) * 256;
  const char* Ag = (const char*)A + (size_t)m0 * 2048;
  const char* Bg = (const char*)Bm + (size_t)n0 * 2048;
  char* A0 = lds;           char* B0 = lds + 32768;
  char* A1 = lds + 65536;   char* B1 = lds + 98304;

  f32x4 acc[8][4];
  f32x4 zero = {0.f, 0.f, 0.f, 0.f};
#pragma unroll
  for (int i = 0; i < 8; i++)
#pragma unroll
    for (int jj = 0; jj < 4; jj++) acc[i][jj] = zero;

  // prologue: tile0 fully (4 half-tiles), tile1 A-h0/B-h0/B-h1 (3 half-tiles)
  stage_half(Ag, A0, 0, 0, tid);
  stage_half(Ag, A0, 0, 1, tid);
  stage_half(Bg, B0, 0, 0, tid);
  stage_half(Bg, B0, 0, 1, tid);
  stage_half(Ag, A1, 1, 0, tid);
  stage_half(Bg, B1, 1, 0, tid);
  stage_half(Bg, B1, 1, 1, tid);
  VMC6();                       // tile0's 8 loads landed; tile1's 6 in flight
  __builtin_amdgcn_s_barrier();
  __builtin_amdgcn_sched_barrier(0);

  for (int j = 0; j < 8; ++j) {
    const int t0 = 2 * j, t1 = 2 * j + 1;
    const bool more = (j < 7);
    bf16x8 aF[4][2], b0F[2][2], b1F[2][2];

    // P1: read A(t0,h0)+B(t0,n0); stage A(t1,h1)
    rdA(aF, A0, wm, 0, lr, lg);
    rdB(b0F, B0, wn, 0, lr, lg);
    stage_half(Ag, A1, t1, 1, tid);
    PH_SYNC_A();
    QUAD(0, 0, aF, b0F);
    PH_SYNC_B();
    // P2: read B(t0,n1); stage A(t0+2,h0)  [A0 rows 0-127 fully consumed at P1]
    rdB(b1F, B0, wn, 1, lr, lg);
    if (more) stage_half(Ag, A0, t0 + 2, 0, tid);
    PH_SYNC_A();
    QUAD(0, 1, aF, b1F);
    PH_SYNC_B();
    // P3: read A(t0,h1); stage B(t0+2,n0)  [B0 rows 0-127 consumed at P1/P2]
    rdA(aF, A0, wm, 1, lr, lg);
    if (more) stage_half(Bg, B0, t0 + 2, 0, tid);
    PH_SYNC_A();
    QUAD(1, 1, aF, b1F);
    PH_SYNC_B();
    // P4: stage B(t0+2,n1); vmcnt gate for tile t1
    if (more) stage_half(Bg, B0, t0 + 2, 1, tid);
    PH_SYNC_A();
    QUAD(1, 0, aF, b0F);
    if (more) VMC6(); else VMC0();
    PH_SYNC_B();
    // P5: read A(t1,h0)+B(t1,n0); stage A(t0+2,h1)  [A0 rows 128-255 consumed at P3]
    rdA(aF, A1, wm, 0, lr, lg);
    rdB(b0F, B1, wn, 0, lr, lg);
    if (more) stage_half(Ag, A0, t0 + 2, 1, tid);
    PH_SYNC_A();
    QUAD(0, 0, aF, b0F);
    PH_SYNC_B();
    // P6: read B(t1,n1); stage A(t1+2,h0)  [A1 rows 0-127 consumed at P5]
    rdB(b1F, B1, wn, 1, lr, lg);
    if (more) stage_half(Ag, A1, t1 + 2, 0, tid);
    PH_SYNC_A();
    QUAD(0, 1, aF, b1F);
    PH_SYNC_B();
    // P7: read A(t1,h1); stage B(t1+2,n0)
    rdA(aF, A1, wm, 1, lr, lg);
    if (more) stage_half(Bg, B1, t1 + 2, 0, tid);
    PH_SYNC_A();
    QUAD(1, 1, aF, b1F);
    PH_SYNC_B();
    // P8: stage B(t1+2,n1); vmcnt gate for tile t0+2
    if (more) stage_half(Bg, B1, t1 + 2, 1, tid);
    PH_SYNC_A();
    QUAD(1, 0, aF, b0F);
    if (more) VMC6();
    PH_SYNC_B();
  }

  // epilogue; acc[mh*4+mt][nh*2+nt]: row = m0 + mh*128 + wm*64 + mt*16 + lg*4+i,
  // col = n0 + wn*64 + nh*32 + nt*16 + lr
#pragma unroll
  for (int mt8 = 0; mt8 < 8; ++mt8) {
    const int mh = mt8 >> 2, mt = mt8 & 3;
#pragma unroll
    for (int nt4 = 0; nt4 < 4; ++nt4) {
      int n = n0 + wn * 64 + nt4 * 16 + lr;
      int mbase = m0 + mh * 128 + wm * 64 + mt * 16 + lg * 4;
      if (MODE == 0) {
        int ty = n >> 10, cc = n & 1023;
        int h = cc >> 6, dd = cc & 63;
        unsigned short* dst = (ty == 0) ? qo : ((ty == 1) ? ko : vo);
        float sc = (ty == 0) ? 0.18033688011111687f : 1.0f;  // (1/8)*log2(e)
#pragma unroll
        for (int i = 0; i < 4; i++) {
          int m = mbase + i;
          int b = m >> 11, tt = m & 2047;
          dst[(((size_t)(b * 16 + h)) * 2048 + tt) * 64 + dd] =
              f2bf(acc[mt8][nt4][i] * sc);
        }
      } else {
        float bv = bias[n];
#pragma unroll
        for (int i = 0; i < 4; i++) {
          int m = mbase + i;
          fout[(size_t)m * 1024 + n] = acc[mt8][nt4][i] + bv;
        }
      }
    }
  }
}

// v [B,H,T,D] -> vt [B,H,D,T]
__global__ __launch_bounds__(256) void transpose_v64(
    const unsigned short* __restrict__ v, unsigned short* __restrict__ vt) {
  __shared__ unsigned short tile[64 * 72];
  int bh = blockIdx.y, t0 = blockIdx.x * 64;
  const unsigned short* vp = v + (size_t)bh * 2048 * 64;
  unsigned short* vtp = vt + (size_t)bh * 64 * 2048;
  int tid = threadIdx.x;
#pragma unroll
  for (int it = 0; it < 2; ++it) {
    int s = tid + it * 256;
    int r = s >> 3, c = (s & 7) * 8;
    *(uint4*)(tile + r * 72 + c) = *(const uint4*)(vp + (size_t)(t0 + r) * 64 + c);
  }
  __syncthreads();
#pragma unroll
  for (int it = 0; it < 2; ++it) {
    int s = tid + it * 256;
    int d = s >> 3, c = (s & 7) * 8;
    unsigned short tmp[8];
#pragma unroll
    for (int j = 0; j < 8; j++) tmp[j] = tile[(c + j) * 72 + d];
    *(uint4*)(vtp + (size_t)d * 2048 + t0 + c) = *(uint4*)tmp;
  }
}

// swizzled LDS read (attn): row stride 128B, byte ^= (row&7)<<4
__device__ __forceinline__ bf16x8 ldsw(const char* base, int row, int cb) {
  return *(const bf16x8*)(base + row * 128 + (cb ^ ((row & 7) << 4)));
}

// Causal flash attention, 8 waves x 32 q-rows (strided: q = q0 + 8*lane + w).
// KV tiles of 64, swapped-operand 32x32x16 MFMA, in-register exp2 softmax,
// defer-max, complementary-pair block order.
__global__ __launch_bounds__(512, 4) void attn_causal(
    const unsigned short* __restrict__ qg, const unsigned short* __restrict__ kg,
    const unsigned short* __restrict__ vtg, unsigned short* __restrict__ og) {
  __shared__ char lds[32768];   // dbuf: [K 8K | Vt 8K] x2; reused for out bounce
  const int tid = threadIdx.x;
  const int w = tid >> 6, l = tid & 63, lo = l & 31, hi = l >> 5;
  const int bh = blockIdx.x;
  const int qc = (0x31204657u >> (blockIdx.y * 4)) & 7;  // complementary pairs
  const int q0 = qc * 256;
  const int nkv = qc * 4 + 4;
  const int b = bh >> 4, h = bh & 15;
  const char* kpB = (const char*)(kg + (size_t)bh * 131072);
  const char* vpB = (const char*)(vtg + (size_t)bh * 131072);
  const unsigned short* qp = qg + (size_t)bh * 131072;
  const int qrow = q0 + 8 * lo + w;

  bf16x8 qf[4];
#pragma unroll
  for (int c = 0; c < 4; ++c)
    qf[c] = *(const bf16x8*)(qp + (size_t)qrow * 64 + hi * 8 + c * 16);

  f32x16 ov[2];
#pragma unroll
  for (int r = 0; r < 16; ++r) { ov[0][r] = 0.f; ov[1][r] = 0.f; }
  const f32x16 zz = {0.f, 0.f, 0.f, 0.f, 0.f, 0.f, 0.f, 0.f,
                     0.f, 0.f, 0.f, 0.f, 0.f, 0.f, 0.f, 0.f};
  float m = -__builtin_inff(), lsum = 0.f;

  const int srow = tid >> 3;
  const int scb = ((tid & 7) * 16) ^ ((srow & 7) << 4);

  gld16(kpB + (size_t)srow * 128 + scb, lds + tid * 16);
  gld16(vpB + (size_t)srow * 4096 + scb, lds + 8192 + tid * 16);
  __syncthreads();

  for (int kt = 0; kt < nkv; ++kt) {
    const int k0 = kt * 64;
    if (kt + 1 < nkv) {
      char* nb = lds + ((kt + 1) & 1) * 16384;
      gld16(kpB + (size_t)(k0 + 64 + srow) * 128 + scb, nb + tid * 16);
      gld16(vpB + (size_t)srow * 4096 + (size_t)(k0 + 64) * 2 + scb, nb + 8192 + tid * 16);
    }
    const char* Kbuf = lds + (kt & 1) * 16384;
    const char* Vbuf = Kbuf + 8192;

    // S^T = K·Q^T (two 32-row k blocks, 4 d-chunks); first chunk uses zero acc
    f32x16 sv[2];
    __builtin_amdgcn_s_setprio(1);
#pragma unroll
    for (int c = 0; c < 4; ++c) {
      bf16x8 kf0 = ldsw(Kbuf, lo, hi * 16 + c * 32);
      bf16x8 kf1 = ldsw(Kbuf, 32 + lo, hi * 16 + c * 32);
      if (c == 0) {
        sv[0] = mfma32(kf0, qf[0], zz);
        sv[1] = mfma32(kf1, qf[0], zz);
      } else {
        sv[0] = mfma32(kf0, qf[c], sv[0]);
        sv[1] = mfma32(kf1, qf[c], sv[1]);
      }
    }
    __builtin_amdgcn_s_setprio(0);

    if (kt >= nkv - 4) {   // causal mask (last 4 tiles only)
#pragma unroll
      for (int t = 0; t < 2; ++t)
#pragma unroll
        for (int r = 0; r < 16; ++r) {
          int kgl = k0 + t * 32 + (r & 3) + 8 * (r >> 2) + 4 * hi;
          if (kgl > qrow) sv[t][r] = -__builtin_inff();
        }
    }

    // tile max via pairwise tree (31 fmax, depth 6)
    float mx[16];
#pragma unroll
    for (int i = 0; i < 16; ++i) mx[i] = fmaxf(sv[0][i], sv[1][i]);
#pragma unroll
    for (int s = 8; s > 0; s >>= 1)
#pragma unroll
      for (int i = 0; i < s; ++i) mx[i] = fmaxf(mx[i], mx[i + s]);
    float tm = fmaxf(mx[0], __shfl_xor(mx[0], 32, 64));

    // defer-max: rescale only when the running max grew by >8 (exp2 domain).
    if (!__all(tm <= m + 8.f)) {
      float nm = fmaxf(fmaxf(m, tm), -1e30f);   // clamp: fully-masked lanes stay sane
      float f = exp2f(m - nm);
      m = nm;
      lsum *= f;
#pragma unroll
      for (int r = 0; r < 16; ++r) { ov[0][r] *= f; ov[1][r] *= f; }
    }

    float ps = 0.f;
#pragma unroll
    for (int t = 0; t < 2; ++t)
#pragma unroll
      for (int r = 0; r < 16; ++r) {
        float p = exp2f(sv[t][r] - m);
        sv[t][r] = p;
        ps += p;
      }
    lsum += ps;

    // P -> bf16 B-frags (cvt_pk + permlane32_swap), then O^T += Vt·P^T
    __builtin_amdgcn_s_setprio(1);
#pragma unroll
    for (int c = 0; c < 4; ++c) {
      const int t = c >> 1, rb = (c & 1) * 8;
      unsigned wA = cvtpk(sv[t][rb + 0], sv[t][rb + 1]);
      unsigned wB = cvtpk(sv[t][rb + 2], sv[t][rb + 3]);
      unsigned wC = cvtpk(sv[t][rb + 4], sv[t][rb + 5]);
      unsigned wD = cvtpk(sv[t][rb + 6], sv[t][rb + 7]);
      asm volatile("v_permlane32_swap_b32 %0, %1" : "+v"(wA), "+v"(wC));
      asm volatile("v_permlane32_swap_b32 %0, %1" : "+v"(wB), "+v"(wD));
      union { uint4 u; bf16x8 h; } pc;
      pc.u.x = wA; pc.u.y = wB; pc.u.z = wC; pc.u.w = wD;
      bf16x8 vf0 = ldsw(Vbuf, lo, hi * 16 + c * 32);
      bf16x8 vf1 = ldsw(Vbuf, 32 + lo, hi * 16 + c * 32);
      ov[0] = mfma32(vf0, pc.h, ov[0]);
      ov[1] = mfma32(vf1, pc.h, ov[1]);
    }
    __builtin_amdgcn_s_setprio(0);
    __syncthreads();
  }

  // epilogue: normalize, bounce through LDS (swizzled) for coalesced stores
  float lt = lsum + __shfl_xor(lsum, 32, 64);
  float inv = 1.0f / lt;
  char* outl = lds + w * 4096;   // per-wave 4KB region: [32 q][64 d] bf16
#pragma unroll
  for (int t2 = 0; t2 < 2; ++t2)
#pragma unroll
    for (int rp = 0; rp < 8; ++rp) {
      const int r = rp * 2;
      const int d0 = (r & 3) + 8 * (r >> 2) + 4 * hi + 32 * t2;
      unsigned pw = cvtpk(ov[t2][r] * inv, ov[t2][r + 1] * inv);
      *(unsigned*)(outl + lo * 128 + ((d0 * 2) ^ ((lo & 7) << 4))) = pw;
    }
  __syncthreads();
  {
    const int qi = l >> 1, cbb = (l & 1) * 64;
    const int t = q0 + 8 * qi + w;
    unsigned short* gp = og + ((size_t)(b * 2048 + t)) * 1024 + h * 64 + (cbb >> 1);
#pragma unroll
    for (int i = 0; i < 4; ++i) {
      uint4 vdat = *(const uint4*)(outl + qi * 128 + ((cbb + i * 16) ^ ((qi & 7) << 4)));
      *(uint4*)(gp + i * 8) = vdat;
    }
  }
}

extern "C" void kernel_launch(void* const* d_in, const int* in_sizes, int n_in,
                              void* d_out, int out_size, void* d_ws, size_t ws_size,
                              hipStream_t stream) {
  const float* x = (const float*)d_in[0];
  const float* Wqkv = (const float*)d_in[1];
  const float* Wout = (const float*)d_in[2];
  const float* bout = (const float*)d_in[3];
  float* out = (float*)d_out;
  char* ws = (char*)d_ws;

  unsigned short* xb = (unsigned short*)(ws);
  unsigned short* wqb = (unsigned short*)(ws + 16777216);
  unsigned short* wob = (unsigned short*)(ws + 23068672);
  unsigned short* qb = (unsigned short*)(ws + 25165824);
  unsigned short* kb = (unsigned short*)(ws + 41943040);
  unsigned short* vb = (unsigned short*)(ws + 58720256);
  unsigned short* vtb = xb;   // x dead after QKV GEMM
  unsigned short* ogb = vb;   // v dead after transpose

  cast_f32_bf16<<<8192, 256, 0, stream>>>(x, xb, 8388608);
  cast_f32_bf16<<<3072, 256, 0, stream>>>(Wqkv, wqb, 3145728);
  cast_f32_bf16<<<1024, 256, 0, stream>>>(Wout, wob, 1048576);

  gemm8p<0><<<dim3(12, 32), 512, 0, stream>>>(xb, wqb, qb, kb, vb, nullptr, nullptr);
  transpose_v64<<<dim3(32, 64), 256, 0, stream>>>(vb, vtb);
  attn_causal<<<dim3(64, 8), 512, 0, stream>>>(qb, kb, vtb, ogb);
  gemm8p<1><<<dim3(4, 32), 512, 0, stream>>>(ogb, wob, nullptr, nullptr, nullptr, bout, out);
}